// Round 3
// baseline (707.425 us; speedup 1.0000x reference)
//
#include <hip/hip_runtime.h>
#include <stdint.h>

// Problem constants (fixed by setup_inputs).
constexpr int NPTS = 8192;
constexpr int DIM  = 64;
constexpr int KNN  = 12;

// Tiling: 64x64 output tile per WG (4 waves, each a 32x32 MFMA tile).
constexpr int RT = 64;               // rows per workgroup
constexpr int CT = 64;               // cols per chunk
constexpr int CS = 8;                // column splits (grid parallelism)
constexpr int STRIPE = NPTS / CS;    // 1024 cols per split
constexpr int NCHUNK = STRIPE / CT;  // 16 chunks
constexpr int LSTR = 72;             // LDS row stride in ushorts (144 B, 16B-aligned, ~2-way = free)
constexpr int CAP  = 28;             // candidate cap per row per round (overflow -> retry round)
constexpr int BSTR = 29;             // odd stride -> conflict-free merge reads

constexpr int NWG_DZ = (NPTS / RT) * CS;   // 1024 WGs; LDS 53.0 KB -> 3 blocks/CU
constexpr int TOT4   = NPTS * NPTS / 4;    // 16,777,216 float4 of mask_X
constexpr int WG4    = TOT4 / NWG_DZ;      // 16384 float4 per WG
constexpr int CH4    = WG4 / NCHUNK;       // 1024 per chunk = 4 per thread

constexpr unsigned long long SENTINEL = 0xFFFFFFFFFFFFFFFFull;

typedef short bf16x8 __attribute__((ext_vector_type(8)));
typedef float f32x4  __attribute__((ext_vector_type(4)));  // native vec: ok for nontemporal builtins

// lgkm-only barrier: fences LDS producer->consumer but does NOT drain vmcnt,
// so in-flight global loads (mask stream, next-chunk stage) survive it.
#define WG_BARRIER() asm volatile("s_waitcnt lgkmcnt(0)\n\ts_barrier" ::: "memory")

__device__ __forceinline__ unsigned short f2bf(float x) {  // RNE f32->bf16
  unsigned u = __float_as_uint(x);
  return (unsigned short)((u + 0x7FFFu + ((u >> 16) & 1u)) >> 16);
}
__device__ __forceinline__ float bf2f(unsigned short h) {
  return __uint_as_float(((unsigned)h) << 16);
}

// Fused init + conv: zero d_out + ecnt, split latent fp32 -> bf16 (hi,lo) + row sumsq.
__global__ __launch_bounds__(256) void prep_kernel(
    const float* __restrict__ latent, unsigned short* __restrict__ Lh,
    unsigned short* __restrict__ Ll, float* __restrict__ sq,
    int* __restrict__ ecnt, float* __restrict__ out) {
  int i = blockIdx.x * 256 + threadIdx.x;  // 32 blocks x 256 = 8192 rows
  ecnt[i] = 0;
  if (i < 4) out[i] = 0.0f;
  const float4* p = reinterpret_cast<const float4*>(latent + (size_t)i * DIM);
  float s = 0.f;
#pragma unroll
  for (int t = 0; t < DIM / 4; ++t) {
    float4 v = p[t];
    s += v.x * v.x + v.y * v.y + v.z * v.z + v.w * v.w;
    ushort4 h, l;
    h.x = f2bf(v.x); l.x = f2bf(v.x - bf2f(h.x));
    h.y = f2bf(v.y); l.y = f2bf(v.y - bf2f(h.y));
    h.z = f2bf(v.z); l.z = f2bf(v.z - bf2f(h.z));
    h.w = f2bf(v.w); l.w = f2bf(v.w - bf2f(h.w));
    *reinterpret_cast<ushort4*>(Lh + (size_t)i * DIM + t * 4) = h;
    *reinterpret_cast<ushort4*>(Ll + (size_t)i * DIM + t * 4) = l;
  }
  sq[i] = s;
}

// Sorted-ascending 12-list insert; cand packs (d2_bits<<32)|j so u64 compare
// == (value, index) lexicographic == JAX stable argsort order.
__device__ __forceinline__ void topk_insert(unsigned long long cand,
                                            unsigned long long pk[KNN]) {
#pragma unroll
  for (int s = KNN - 1; s >= 0; --s) {
    bool belongs = cand < pk[s];
    bool shift = (s > 0) && (cand < pk[s - 1]);
    unsigned long long nv = shift ? pk[s - 1] : cand;
    if (belongs) pk[s] = nv;
  }
}

__device__ __forceinline__ void push_edge(int pos, int* __restrict__ ecnt,
                                          int* __restrict__ ecol) {
  int i = pos >> 13, j = pos & (NPTS - 1);
  int slot = atomicAdd(&ecnt[i], 1);
  if (slot < KNN) ecol[i * KNN + slot] = j;
}

// Gram + top-k, software-pipelined (double-buffered B), mask_X scan fused in.
// A-fragments live in registers (chunk-invariant); 2 lgkm-barriers per chunk.
// Candidate overflow (cap 28 < 64) handled by a retry loop that re-pushes from
// the live acc registers under the tightened threshold; terminates in <=3
// rounds (each round stores >= min(remaining, 28) per row).
__global__ __launch_bounds__(256, 3) void main_kernel(
    const unsigned short* __restrict__ Lh, const unsigned short* __restrict__ Ll,
    const float* __restrict__ sq, unsigned long long* __restrict__ topk_ws,
    const float* __restrict__ mask_X, int* __restrict__ ecnt,
    int* __restrict__ ecol) {
  __shared__ unsigned short Bh[2 * CT * LSTR], Bl[2 * CT * LSTR];  // 36.9 KB
  __shared__ float d2b[RT * BSTR];                                 // 7.4 KB
  __shared__ int   colb[RT * BSTR];                                // 7.4 KB
  __shared__ int   cnt[RT];
  __shared__ float thr[RT];  // running 12th-smallest d2 per row
  __shared__ float sqA[RT];
  __shared__ float sqB[2][CT];
  __shared__ int   ovf;      // any row overflowed this round -> retry

  const int tid = threadIdx.x;
  const int tile = blockIdx.x / CS;
  const int split = blockIdx.x % CS;
  const int ib = tile * RT;
  const int jb0 = split * STRIPE;

  const int wid = tid >> 6;
  const int lane = tid & 63;
  const int quad = lane >> 4;
  const int l16 = lane & 15;
  const int wr = wid >> 1;
  const int wc = wid & 1;

  // A fragments: global -> registers, once (L2-hot).
  bf16x8 ahr[2][2], alr[2][2];  // [kk][rb]
#pragma unroll
  for (int kk = 0; kk < 2; ++kk) {
    const int ko = kk * 32 + quad * 8;
#pragma unroll
    for (int rb = 0; rb < 2; ++rb) {
      const int row = ib + wr * 32 + rb * 16 + l16;
      ahr[kk][rb] = *reinterpret_cast<const bf16x8*>(Lh + (size_t)row * DIM + ko);
      alr[kk][rb] = *reinterpret_cast<const bf16x8*>(Ll + (size_t)row * DIM + ko);
    }
  }
  if (tid < RT) { sqA[tid] = sq[ib + tid]; thr[tid] = 3.4e38f; cnt[tid] = 0; }

  // Prologue: stage chunk 0 into buffer 0.
  {
#pragma unroll
    for (int it = 0; it < 2; ++it) {
      int f = it * 256 + tid, r = f >> 3, c = f & 7;
      uint4 vh = *reinterpret_cast<const uint4*>(Lh + (size_t)(jb0 + r) * DIM + c * 8);
      uint4 vl = *reinterpret_cast<const uint4*>(Ll + (size_t)(jb0 + r) * DIM + c * 8);
      *reinterpret_cast<uint4*>(&Bh[r * LSTR + c * 8]) = vh;
      *reinterpret_cast<uint4*>(&Bl[r * LSTR + c * 8]) = vl;
    }
    if (tid < CT) sqB[0][tid] = sq[jb0 + tid];
  }
  __syncthreads();

  const f32x4* mbase = reinterpret_cast<const f32x4*>(mask_X);
  const int wgBase4 = blockIdx.x * WG4;

  unsigned long long pk[KNN];
#pragma unroll
  for (int t = 0; t < KNN; ++t) pk[t] = SENTINEL;

  for (int ch = 0; ch < NCHUNK; ++ch) {
    const int cur = ch & 1, nxt = cur ^ 1;
    const int jb = jb0 + ch * CT;
    const bool have_next = (ch + 1 < NCHUNK);

    // Issue next-chunk staging loads (latency hidden under this chunk's MFMA).
    uint4 vh0, vl0, vh1, vl1;
    float sqn = 0.f;
    if (have_next) {
      {
        int f = tid, r = f >> 3, c = f & 7;
        vh0 = *reinterpret_cast<const uint4*>(Lh + (size_t)(jb + CT + r) * DIM + c * 8);
        vl0 = *reinterpret_cast<const uint4*>(Ll + (size_t)(jb + CT + r) * DIM + c * 8);
      }
      {
        int f = 256 + tid, r = f >> 3, c = f & 7;
        vh1 = *reinterpret_cast<const uint4*>(Lh + (size_t)(jb + CT + r) * DIM + c * 8);
        vl1 = *reinterpret_cast<const uint4*>(Ll + (size_t)(jb + CT + r) * DIM + c * 8);
      }
      if (tid < CT) sqn = sq[jb + CT + tid];
    }
    // Mask stream for this chunk: issued now, consumed after merge (~full
    // chunk of latency coverage). Issued after staging so the staging
    // ds_write's auto-vmcnt leaves these in flight.
    f32x4 m[4];
    const int mb = wgBase4 + ch * CH4 + tid;
#pragma unroll
    for (int q = 0; q < 4; ++q)
      m[q] = __builtin_nontemporal_load(&mbase[mb + q * 256]);
    __builtin_amdgcn_sched_barrier(0);  // pin all issues above the compute

    // Gram via split-bf16 MFMA on B[cur]: hi*hi + hi*lo + lo*hi.
    const int bbase = cur * CT * LSTR;
    f32x4 acc[2][2];
#pragma unroll
    for (int rb = 0; rb < 2; ++rb)
#pragma unroll
      for (int cb = 0; cb < 2; ++cb) acc[rb][cb] = (f32x4){0.f, 0.f, 0.f, 0.f};

#pragma unroll
    for (int kk = 0; kk < 2; ++kk) {
      const int ko = kk * 32 + quad * 8;
      bf16x8 bh[2], bl[2];
#pragma unroll
      for (int cb = 0; cb < 2; ++cb) {
        int col = wc * 32 + cb * 16 + l16;
        bh[cb] = *reinterpret_cast<const bf16x8*>(&Bh[bbase + col * LSTR + ko]);
        bl[cb] = *reinterpret_cast<const bf16x8*>(&Bl[bbase + col * LSTR + ko]);
      }
#pragma unroll
      for (int rb = 0; rb < 2; ++rb)
#pragma unroll
        for (int cb = 0; cb < 2; ++cb) {
          acc[rb][cb] = __builtin_amdgcn_mfma_f32_16x16x32_bf16(ahr[kk][rb], bh[cb], acc[rb][cb], 0, 0, 0);
          acc[rb][cb] = __builtin_amdgcn_mfma_f32_16x16x32_bf16(ahr[kk][rb], bl[cb], acc[rb][cb], 0, 0, 0);
          acc[rb][cb] = __builtin_amdgcn_mfma_f32_16x16x32_bf16(alr[kk][rb], bh[cb], acc[rb][cb], 0, 0, 0);
        }
    }

    // Push + merge, with overflow-retry. C/D layout: col=lane&15, row=quad*4+reg.
    unsigned todo = 0xFFFFu;  // 16 candidate slots per thread
    int round = 0;
    do {
#pragma unroll
      for (int rb = 0; rb < 2; ++rb) {
#pragma unroll
        for (int r = 0; r < 4; ++r) {
          const int rl = wr * 32 + rb * 16 + quad * 4 + r;
          const int gi = ib + rl;
          const float sa = sqA[rl];
          const float tt = thr[rl];
#pragma unroll
          for (int cb = 0; cb < 2; ++cb) {
            const unsigned bit = 1u << (rb * 8 + r * 2 + cb);
            if (todo & bit) {
              const int col_l = wc * 32 + cb * 16 + l16;
              const int gj = jb + col_l;
              float d2 = sa + sqB[cur][col_l] - 2.0f * acc[rb][cb][r];
              float d2c = fmaxf(d2, 0.0f);
              if (d2c < tt && gj != gi) {
                int pos = atomicAdd(&cnt[rl], 1);
                if (pos < CAP) {
                  d2b[rl * BSTR + pos] = d2c;
                  colb[rl * BSTR + pos] = gj;
                  todo &= ~bit;
                }
                // else: retry next round under tightened thr
              } else {
                todo &= ~bit;  // filtered: can never enter final top-12
              }
            }
          }
        }
      }
      if (round == 0 && have_next) {
        // Write prefetched next chunk into the other buffer (waits only its
        // own vmcnt; mask loads issued after it stay in flight).
        const int boff = nxt * CT * LSTR;
        { int f = tid, r = f >> 3, c = f & 7;
          *reinterpret_cast<uint4*>(&Bh[boff + r * LSTR + c * 8]) = vh0;
          *reinterpret_cast<uint4*>(&Bl[boff + r * LSTR + c * 8]) = vl0; }
        { int f = 256 + tid, r = f >> 3, c = f & 7;
          *reinterpret_cast<uint4*>(&Bh[boff + r * LSTR + c * 8]) = vh1;
          *reinterpret_cast<uint4*>(&Bl[boff + r * LSTR + c * 8]) = vl1; }
        if (tid < CT) sqB[nxt][tid] = sqn;
      }
      WG_BARRIER();  // (C) pushes + next-B visible

      if (tid < RT) {  // wave 0: per-row serial merge (conflict-free reads)
        const int nraw = cnt[tid];
        const int n = nraw > CAP ? CAP : nraw;
        for (int t = 0; t < n; ++t) {
          unsigned long long cand =
              ((unsigned long long)__float_as_uint(d2b[tid * BSTR + t]) << 32) |
              (unsigned)colb[tid * BSTR + t];
          if (cand < pk[KNN - 1]) topk_insert(cand, pk);
        }
        thr[tid] = __uint_as_float((unsigned)(pk[KNN - 1] >> 32));
        cnt[tid] = 0;
        bool o = nraw > CAP;
        bool anyo = __any(o);  // wave 0 fully active here
        if (tid == 0) ovf = anyo ? 1 : 0;
      }
      if (round == 0) {
        // Consume the mask stream (all waves; overlaps wave-0 merge tail).
#pragma unroll
        for (int q = 0; q < 4; ++q) {
          f32x4 mv = m[q];
          if (mv[0] == 0.f && mv[1] == 0.f && mv[2] == 0.f && mv[3] == 0.f) continue;
          const int base = (mb + q * 256) * 4;
          if (mv[0] != 0.f) push_edge(base + 0, ecnt, ecol);
          if (mv[1] != 0.f) push_edge(base + 1, ecnt, ecol);
          if (mv[2] != 0.f) push_edge(base + 2, ecnt, ecol);
          if (mv[3] != 0.f) push_edge(base + 3, ecnt, ecol);
        }
      }
      WG_BARRIER();  // (A) thr/cnt/ovf visible
      ++round;
    } while (ovf != 0);
  }

  // Per-(row,split) partial top-12 to workspace.
  if (tid < RT) {
    size_t base = ((size_t)(ib + tid) * CS + split) * KNN;
#pragma unroll
    for (int t = 0; t < KNN; ++t) topk_ws[base + t] = pk[t];
  }
}

// Fused tail: blocks [0,384) = distance1_2 over X-edges; blocks [384,416) =
// per-row merge of CS partials + distance2_1 + matched count.
__global__ __launch_bounds__(256) void tail_kernel(
    const float* __restrict__ latent, const float* __restrict__ latent_norm,
    const float* __restrict__ dist_X, const int* __restrict__ ecol,
    const unsigned long long* __restrict__ topk_ws, float* __restrict__ d_out) {
  __shared__ float red[256];
  const int tid = threadIdx.x;
  const float invnorm = 1.0f / latent_norm[0];

  if (blockIdx.x < (NPTS * KNN / 256)) {
    // --- sig1: dz from exact fp32 dot; dx gathered from dist_X directly.
    const int e = blockIdx.x * 256 + tid;  // e < NPTS*KNN exactly
    int i = e / KNN;
    int j = ecol[e];
    float dx = dist_X[(size_t)i * NPTS + j];
    const float4* a = reinterpret_cast<const float4*>(latent + (size_t)i * DIM);
    const float4* b = reinterpret_cast<const float4*>(latent + (size_t)j * DIM);
    float d2 = 0.f;
#pragma unroll
    for (int t = 0; t < DIM / 4; ++t) {
      float4 va = a[t], vb = b[t];
      float ex = va.x - vb.x, ey = va.y - vb.y, ez = va.z - vb.z, ew = va.w - vb.w;
      d2 += ex * ex + ey * ey + ez * ez + ew * ew;
    }
    float dz = (d2 > 0.f) ? sqrtf(d2) * invnorm : 0.f;
    float diff = dx - dz;

    red[tid] = diff * diff;
    __syncthreads();
    for (int s = 128; s > 0; s >>= 1) {
      if (tid < s) red[tid] += red[tid + s];
      __syncthreads();
    }
    if (tid == 0) {
      atomicAdd(&d_out[2], red[0]);
      atomicAdd(&d_out[0], red[0]);
    }
  } else {
    // --- finalize
    const int gi = (blockIdx.x - NPTS * KNN / 256) * 256 + tid;

    unsigned long long pk[KNN];
#pragma unroll
    for (int t = 0; t < KNN; ++t) pk[t] = SENTINEL;

    const unsigned long long* src = topk_ws + (size_t)gi * CS * KNN;
    for (int t = 0; t < CS * KNN; ++t) {
      unsigned long long cand = src[t];
      if (cand < pk[KNN - 1]) topk_insert(cand, pk);
    }

    int ec[KNN];
#pragma unroll
    for (int t = 0; t < KNN; ++t) ec[t] = ecol[gi * KNN + t];

    float acc2 = 0.f, accc = 0.f;
#pragma unroll
    for (int t = 0; t < KNN; ++t) {
      int j = (int)(unsigned)(pk[t] & 0xFFFFFFFFull);
      float d2 = __uint_as_float((unsigned)(pk[t] >> 32));
      float dz = (d2 > 0.0f) ? sqrtf(d2) * invnorm : 0.0f;
      float dxv = dist_X[(size_t)gi * NPTS + j];
      float diff = dxv - dz;
      acc2 += diff * diff;
      int hit = 0;
#pragma unroll
      for (int s = 0; s < KNN; ++s) hit |= (ec[s] == j);
      accc += (float)hit;  // Z-edge also present in X-mask
    }

    red[tid] = acc2;
    __syncthreads();
    for (int s = 128; s > 0; s >>= 1) {
      if (tid < s) red[tid] += red[tid + s];
      __syncthreads();
    }
    float racc2 = red[0];
    __syncthreads();
    red[tid] = accc;
    __syncthreads();
    for (int s = 128; s > 0; s >>= 1) {
      if (tid < s) red[tid] += red[tid + s];
      __syncthreads();
    }
    if (tid == 0) {
      atomicAdd(&d_out[3], racc2);
      atomicAdd(&d_out[0], racc2);
      atomicAdd(&d_out[1], red[0] * (1.0f / ((float)NPTS * (float)KNN)));
    }
  }
}

extern "C" void kernel_launch(void* const* d_in, const int* in_sizes, int n_in,
                              void* d_out, int out_size, void* d_ws,
                              size_t ws_size, hipStream_t stream) {
  const float* latent      = (const float*)d_in[0];
  const float* latent_norm = (const float*)d_in[1];
  const float* dist_X      = (const float*)d_in[2];
  const float* mask_X      = (const float*)d_in[3];
  float* out = (float*)d_out;

  // Workspace layout (all 16B-aligned).
  char* w = (char*)d_ws;
  float*          sq   = (float*)w;                    w += NPTS * 4;            // 32 KB
  unsigned short* Lh   = (unsigned short*)w;           w += NPTS * DIM * 2;      // 1 MB
  unsigned short* Ll   = (unsigned short*)w;           w += NPTS * DIM * 2;      // 1 MB
  int*            ecnt = (int*)w;                      w += NPTS * 4;            // 32 KB
  int*            ecol = (int*)w;                      w += NPTS * KNN * 4;      // 384 KB
  unsigned long long* topk = (unsigned long long*)w;   // 6.3 MB (CS=8)

  prep_kernel<<<NPTS / 256, 256, 0, stream>>>(latent, Lh, Ll, sq, ecnt, out);
  main_kernel<<<NWG_DZ, 256, 0, stream>>>(Lh, Ll, sq, topk, mask_X, ecnt, ecol);
  tail_kernel<<<NPTS * KNN / 256 + NPTS / 256, 256, 0, stream>>>(
      latent, latent_norm, dist_X, ecol, topk, out);
}

// Round 5
// 616.975 us; speedup vs baseline: 1.1466x; 1.1466x over previous
//
#include <hip/hip_runtime.h>
#include <stdint.h>

// Problem constants (fixed by setup_inputs).
constexpr int NPTS = 8192;
constexpr int DIM  = 64;
constexpr int KNN  = 12;

// Tiling: 64x64 output tile per WG (4 waves, each a 32x32 MFMA tile).
constexpr int RT = 64;               // rows per workgroup
constexpr int CT = 64;               // cols per chunk
constexpr int CS = 4;                // column splits (grid parallelism)
constexpr int STRIPE = NPTS / CS;    // 2048 cols per split
constexpr int NCHUNK = STRIPE / CT;  // 32 chunks
constexpr int LSTR = 72;             // LDS row stride in ushorts (144 B, 16B-aligned, ~2-way = free)
constexpr int BSTR = 65;             // odd stride -> conflict-free merge reads (cap 64 never overflows)

constexpr int NWG_DZ = (NPTS / RT) * CS;   // 512 WGs = exactly 2 blocks/CU, 1 dispatch wave
constexpr int TOT4   = NPTS * NPTS / 4;    // 16,777,216 float4 of mask_X
constexpr int WG4    = TOT4 / NWG_DZ;      // 32768 float4 per WG
constexpr int CH4    = WG4 / NCHUNK;       // 1024 per chunk = 4 per thread

constexpr unsigned long long SENTINEL = 0xFFFFFFFFFFFFFFFFull;

typedef short bf16x8 __attribute__((ext_vector_type(8)));
typedef float f32x4  __attribute__((ext_vector_type(4)));  // native vec: ok for nontemporal builtins

// lgkm-only barrier: fences LDS producer->consumer but does NOT drain vmcnt,
// so in-flight global loads (mask stream, next-chunk stage) survive it.
#define WG_BARRIER() asm volatile("s_waitcnt lgkmcnt(0)\n\ts_barrier" ::: "memory")

__device__ __forceinline__ unsigned short f2bf(float x) {  // RNE f32->bf16
  unsigned u = __float_as_uint(x);
  return (unsigned short)((u + 0x7FFFu + ((u >> 16) & 1u)) >> 16);
}
__device__ __forceinline__ float bf2f(unsigned short h) {
  return __uint_as_float(((unsigned)h) << 16);
}

// Fused init + conv, 8 threads per row (256 blocks -> all CUs busy).
__global__ __launch_bounds__(256) void prep_kernel(
    const float* __restrict__ latent, unsigned short* __restrict__ Lh,
    unsigned short* __restrict__ Ll, float* __restrict__ sq,
    int* __restrict__ ecnt, float* __restrict__ out) {
  const int gid = blockIdx.x * 256 + threadIdx.x;  // 65536 threads
  const int r = gid >> 3, o = gid & 7;             // row, octant (8 floats each)
  if (gid < 4) out[gid] = 0.0f;
  if (o == 0) ecnt[r] = 0;

  const float4* p = reinterpret_cast<const float4*>(latent + (size_t)r * DIM + o * 8);
  float4 v0 = p[0], v1 = p[1];
  float s = v0.x * v0.x + v0.y * v0.y + v0.z * v0.z + v0.w * v0.w +
            v1.x * v1.x + v1.y * v1.y + v1.z * v1.z + v1.w * v1.w;

  ushort4 h0, l0, h1, l1;
  h0.x = f2bf(v0.x); l0.x = f2bf(v0.x - bf2f(h0.x));
  h0.y = f2bf(v0.y); l0.y = f2bf(v0.y - bf2f(h0.y));
  h0.z = f2bf(v0.z); l0.z = f2bf(v0.z - bf2f(h0.z));
  h0.w = f2bf(v0.w); l0.w = f2bf(v0.w - bf2f(h0.w));
  h1.x = f2bf(v1.x); l1.x = f2bf(v1.x - bf2f(h1.x));
  h1.y = f2bf(v1.y); l1.y = f2bf(v1.y - bf2f(h1.y));
  h1.z = f2bf(v1.z); l1.z = f2bf(v1.z - bf2f(h1.z));
  h1.w = f2bf(v1.w); l1.w = f2bf(v1.w - bf2f(h1.w));
  ushort4* dh = reinterpret_cast<ushort4*>(Lh + (size_t)r * DIM + o * 8);
  ushort4* dl = reinterpret_cast<ushort4*>(Ll + (size_t)r * DIM + o * 8);
  dh[0] = h0; dh[1] = h1;
  dl[0] = l0; dl[1] = l1;

  s += __shfl_xor(s, 1);
  s += __shfl_xor(s, 2);
  s += __shfl_xor(s, 4);
  if (o == 0) sq[r] = s;
}

// Sorted-ascending 12-list insert; cand packs (d2_bits<<32)|j so u64 compare
// == (value, index) lexicographic == JAX stable argsort order.
__device__ __forceinline__ void topk_insert(unsigned long long cand,
                                            unsigned long long pk[KNN]) {
#pragma unroll
  for (int s = KNN - 1; s >= 0; --s) {
    bool belongs = cand < pk[s];
    bool shift = (s > 0) && (cand < pk[s - 1]);
    unsigned long long nv = shift ? pk[s - 1] : cand;
    if (belongs) pk[s] = nv;
  }
}

__device__ __forceinline__ void push_edge(int pos, const float* __restrict__ dist_X,
                                          int* __restrict__ ecnt,
                                          int* __restrict__ ecol,
                                          float* __restrict__ edx) {
  int i = pos >> 13, j = pos & (NPTS - 1);
  int slot = atomicAdd(&ecnt[i], 1);
  if (slot < KNN) {
    ecol[i * KNN + slot] = j;
    edx[i * KNN + slot] = dist_X[pos];  // fire-and-forget gather, latency hidden
  }
}

// Gram + top-k, double-buffered B pipeline, mask_X scan + edx capture fused in.
// A-fragments in registers (chunk-invariant); 2 lgkm-barriers per chunk.
__global__ __launch_bounds__(256, 2) void main_kernel(
    const unsigned short* __restrict__ Lh, const unsigned short* __restrict__ Ll,
    const float* __restrict__ sq, unsigned long long* __restrict__ topk_ws,
    const float* __restrict__ mask_X, const float* __restrict__ dist_X,
    int* __restrict__ ecnt, int* __restrict__ ecol, float* __restrict__ edx) {
  __shared__ unsigned short Bh[2 * CT * LSTR], Bl[2 * CT * LSTR];  // 36.9 KB
  __shared__ float d2b[RT * BSTR];                                 // 16.6 KB
  __shared__ int   colb[RT * BSTR];                                // 16.6 KB
  __shared__ int   cnt[RT];
  __shared__ float thr[RT];  // running 12th-smallest d2 per row
  __shared__ float sqA[RT];
  __shared__ float sqB[2][CT];

  const int tid = threadIdx.x;
  const int tile = blockIdx.x / CS;
  const int split = blockIdx.x % CS;
  const int ib = tile * RT;
  const int jb0 = split * STRIPE;

  const int wid = tid >> 6;
  const int lane = tid & 63;
  const int quad = lane >> 4;
  const int l16 = lane & 15;
  const int wr = wid >> 1;
  const int wc = wid & 1;

  // A fragments: global -> registers, once (L2-hot).
  bf16x8 ahr[2][2], alr[2][2];  // [kk][rb]
#pragma unroll
  for (int kk = 0; kk < 2; ++kk) {
    const int ko = kk * 32 + quad * 8;
#pragma unroll
    for (int rb = 0; rb < 2; ++rb) {
      const int row = ib + wr * 32 + rb * 16 + l16;
      ahr[kk][rb] = *reinterpret_cast<const bf16x8*>(Lh + (size_t)row * DIM + ko);
      alr[kk][rb] = *reinterpret_cast<const bf16x8*>(Ll + (size_t)row * DIM + ko);
    }
  }
  if (tid < RT) { sqA[tid] = sq[ib + tid]; thr[tid] = 3.4e38f; cnt[tid] = 0; }

  // Prologue: stage chunk 0 into buffer 0.
  {
#pragma unroll
    for (int it = 0; it < 2; ++it) {
      int f = it * 256 + tid, r = f >> 3, c = f & 7;
      uint4 vh = *reinterpret_cast<const uint4*>(Lh + (size_t)(jb0 + r) * DIM + c * 8);
      uint4 vl = *reinterpret_cast<const uint4*>(Ll + (size_t)(jb0 + r) * DIM + c * 8);
      *reinterpret_cast<uint4*>(&Bh[r * LSTR + c * 8]) = vh;
      *reinterpret_cast<uint4*>(&Bl[r * LSTR + c * 8]) = vl;
    }
    if (tid < CT) sqB[0][tid] = sq[jb0 + tid];
  }
  __syncthreads();

  const f32x4* mbase = reinterpret_cast<const f32x4*>(mask_X);
  const int wgBase4 = blockIdx.x * WG4;

  unsigned long long pk[KNN];
#pragma unroll
  for (int t = 0; t < KNN; ++t) pk[t] = SENTINEL;

  for (int ch = 0; ch < NCHUNK; ++ch) {
    const int cur = ch & 1, nxt = cur ^ 1;
    const int jb = jb0 + ch * CT;
    const bool have_next = (ch + 1 < NCHUNK);

    // Issue next-chunk staging loads FIRST (so ds_write's vmcnt wait later
    // leaves the mask loads, issued after, still in flight).
    uint4 vh0, vl0, vh1, vl1;
    float sqn = 0.f;
    if (have_next) {
      { int f = tid, r = f >> 3, c = f & 7;
        vh0 = *reinterpret_cast<const uint4*>(Lh + (size_t)(jb + CT + r) * DIM + c * 8);
        vl0 = *reinterpret_cast<const uint4*>(Ll + (size_t)(jb + CT + r) * DIM + c * 8); }
      { int f = 256 + tid, r = f >> 3, c = f & 7;
        vh1 = *reinterpret_cast<const uint4*>(Lh + (size_t)(jb + CT + r) * DIM + c * 8);
        vl1 = *reinterpret_cast<const uint4*>(Ll + (size_t)(jb + CT + r) * DIM + c * 8); }
      if (tid < CT) sqn = sq[jb + CT + tid];
    }
    // Mask stream for this chunk: issued now, consumed after the merge.
    f32x4 m[4];
    const int mb = wgBase4 + ch * CH4 + tid;
#pragma unroll
    for (int q = 0; q < 4; ++q)
      m[q] = __builtin_nontemporal_load(&mbase[mb + q * 256]);
    __builtin_amdgcn_sched_barrier(0);  // pin all issues above the compute

    // Gram via split-bf16 MFMA on B[cur]: hi*hi + hi*lo + lo*hi.
    const int bbase = cur * CT * LSTR;
    f32x4 acc[2][2];
#pragma unroll
    for (int rb = 0; rb < 2; ++rb)
#pragma unroll
      for (int cb = 0; cb < 2; ++cb) acc[rb][cb] = (f32x4){0.f, 0.f, 0.f, 0.f};

#pragma unroll
    for (int kk = 0; kk < 2; ++kk) {
      const int ko = kk * 32 + quad * 8;
      bf16x8 bh[2], bl[2];
#pragma unroll
      for (int cb = 0; cb < 2; ++cb) {
        int col = wc * 32 + cb * 16 + l16;
        bh[cb] = *reinterpret_cast<const bf16x8*>(&Bh[bbase + col * LSTR + ko]);
        bl[cb] = *reinterpret_cast<const bf16x8*>(&Bl[bbase + col * LSTR + ko]);
      }
#pragma unroll
      for (int rb = 0; rb < 2; ++rb)
#pragma unroll
        for (int cb = 0; cb < 2; ++cb) {
          acc[rb][cb] = __builtin_amdgcn_mfma_f32_16x16x32_bf16(ahr[kk][rb], bh[cb], acc[rb][cb], 0, 0, 0);
          acc[rb][cb] = __builtin_amdgcn_mfma_f32_16x16x32_bf16(ahr[kk][rb], bl[cb], acc[rb][cb], 0, 0, 0);
          acc[rb][cb] = __builtin_amdgcn_mfma_f32_16x16x32_bf16(alr[kk][rb], bh[cb], acc[rb][cb], 0, 0, 0);
        }
    }

    // Epilogue: d2 + candidate push (cap 64 can't overflow; SoA conflict-free).
    // C/D layout (verified): col = lane&15, row = quad*4 + reg.
#pragma unroll
    for (int rb = 0; rb < 2; ++rb) {
      const int row0 = wr * 32 + rb * 16 + quad * 4;
#pragma unroll
      for (int r = 0; r < 4; ++r) {
        const int rl = row0 + r;
        const int gi = ib + rl;
        const float sa = sqA[rl];
        const float tt = thr[rl];
#pragma unroll
        for (int cb = 0; cb < 2; ++cb) {
          const int col_l = wc * 32 + cb * 16 + l16;
          const int gj = jb + col_l;
          float d2 = sa + sqB[cur][col_l] - 2.0f * acc[rb][cb][r];
          float d2c = fmaxf(d2, 0.0f);
          if (d2c < tt && gj != gi) {
            int pos = atomicAdd(&cnt[rl], 1);  // pos <= 63 < BSTR guaranteed
            d2b[rl * BSTR + pos] = d2c;
            colb[rl * BSTR + pos] = gj;
          }
        }
      }
    }

    // Write prefetched next chunk into the other buffer (after epilogue, so
    // the stage loads had the whole MFMA+epilogue to land; waits vmcnt only
    // down to the 4 mask loads, which stay in flight).
    __builtin_amdgcn_sched_barrier(0);
    if (have_next) {
      const int boff = nxt * CT * LSTR;
      { int f = tid, r = f >> 3, c = f & 7;
        *reinterpret_cast<uint4*>(&Bh[boff + r * LSTR + c * 8]) = vh0;
        *reinterpret_cast<uint4*>(&Bl[boff + r * LSTR + c * 8]) = vl0; }
      { int f = 256 + tid, r = f >> 3, c = f & 7;
        *reinterpret_cast<uint4*>(&Bh[boff + r * LSTR + c * 8]) = vh1;
        *reinterpret_cast<uint4*>(&Bl[boff + r * LSTR + c * 8]) = vl1; }
      if (tid < CT) sqB[nxt][tid] = sqn;
    }
    WG_BARRIER();  // (C) pushes + next-B visible

    if (tid < RT) {  // wave 0: per-row serial merge (conflict-free reads)
      const int n = cnt[tid];
      for (int t = 0; t < n; ++t) {
        unsigned long long cand =
            ((unsigned long long)__float_as_uint(d2b[tid * BSTR + t]) << 32) |
            (unsigned)colb[tid * BSTR + t];
        if (cand < pk[KNN - 1]) topk_insert(cand, pk);
      }
      thr[tid] = __uint_as_float((unsigned)(pk[KNN - 1] >> 32));
      cnt[tid] = 0;
    }
    // Consume the mask stream (waves 1-3 overlap wave-0's merge).
#pragma unroll
    for (int q = 0; q < 4; ++q) {
      f32x4 mv = m[q];
      if (mv[0] == 0.f && mv[1] == 0.f && mv[2] == 0.f && mv[3] == 0.f) continue;
      const int base = (mb + q * 256) * 4;
      if (mv[0] != 0.f) push_edge(base + 0, dist_X, ecnt, ecol, edx);
      if (mv[1] != 0.f) push_edge(base + 1, dist_X, ecnt, ecol, edx);
      if (mv[2] != 0.f) push_edge(base + 2, dist_X, ecnt, ecol, edx);
      if (mv[3] != 0.f) push_edge(base + 3, dist_X, ecnt, ecol, edx);
    }
    WG_BARRIER();  // (A) thr/cnt visible for next chunk
  }

  // Per-(row,split) partial top-12 to workspace.
  if (tid < RT) {
    size_t base = ((size_t)(ib + tid) * CS + split) * KNN;
#pragma unroll
    for (int t = 0; t < KNN; ++t) topk_ws[base + t] = pk[t];
  }
}

// Fused tail: blocks [0,384) = distance1_2 over X-edges (dx from edx, linear);
// blocks [384,512) = per-row merge of CS partials + distance2_1 + matched,
// 64 rows per block (wave 0 only) -> 128 CUs instead of 32.
__global__ __launch_bounds__(256) void tail_kernel(
    const float* __restrict__ latent, const float* __restrict__ latent_norm,
    const float* __restrict__ dist_X, const int* __restrict__ ecol,
    const float* __restrict__ edx, const unsigned long long* __restrict__ topk_ws,
    float* __restrict__ d_out) {
  const int tid = threadIdx.x;
  const float invnorm = 1.0f / latent_norm[0];

  if (blockIdx.x < (NPTS * KNN / 256)) {
    __shared__ float red[256];
    // --- sig1: dz from exact fp32 dot; dx streamed from edx (coalesced).
    const int e = blockIdx.x * 256 + tid;  // e < NPTS*KNN exactly
    int i = e / KNN;
    int j = ecol[e];
    float dx = edx[e];
    const float4* a = reinterpret_cast<const float4*>(latent + (size_t)i * DIM);
    const float4* b = reinterpret_cast<const float4*>(latent + (size_t)j * DIM);
    float d2 = 0.f;
#pragma unroll
    for (int t = 0; t < DIM / 4; ++t) {
      float4 va = a[t], vb = b[t];
      float ex = va.x - vb.x, ey = va.y - vb.y, ez = va.z - vb.z, ew = va.w - vb.w;
      d2 += ex * ex + ey * ey + ez * ez + ew * ew;
    }
    float dz = (d2 > 0.f) ? sqrtf(d2) * invnorm : 0.f;
    float diff = dx - dz;

    red[tid] = diff * diff;
    __syncthreads();
    for (int s = 128; s > 0; s >>= 1) {
      if (tid < s) red[tid] += red[tid + s];
      __syncthreads();
    }
    if (tid == 0) {
      atomicAdd(&d_out[2], red[0]);
      atomicAdd(&d_out[0], red[0]);
    }
  } else {
    // --- finalize: wave 0 only, one row per lane.
    if (tid >= 64) return;
    const int gi = (blockIdx.x - NPTS * KNN / 256) * 64 + tid;

    unsigned long long pk[KNN];
#pragma unroll
    for (int t = 0; t < KNN; ++t) pk[t] = SENTINEL;

    const unsigned long long* src = topk_ws + (size_t)gi * CS * KNN;
    for (int t = 0; t < CS * KNN; ++t) {
      unsigned long long cand = src[t];
      if (cand < pk[KNN - 1]) topk_insert(cand, pk);
    }

    int ec[KNN];
#pragma unroll
    for (int t = 0; t < KNN; ++t) ec[t] = ecol[gi * KNN + t];

    float acc2 = 0.f, accc = 0.f;
#pragma unroll
    for (int t = 0; t < KNN; ++t) {
      int j = (int)(unsigned)(pk[t] & 0xFFFFFFFFull);
      float d2 = __uint_as_float((unsigned)(pk[t] >> 32));
      float dz = (d2 > 0.0f) ? sqrtf(d2) * invnorm : 0.0f;
      float dxv = dist_X[(size_t)gi * NPTS + j];
      float diff = dxv - dz;
      acc2 += diff * diff;
      int hit = 0;
#pragma unroll
      for (int s = 0; s < KNN; ++s) hit |= (ec[s] == j);
      accc += (float)hit;  // Z-edge also present in X-mask
    }

    // Wave-level reduce, lane 0 atomics.
#pragma unroll
    for (int s = 32; s > 0; s >>= 1) {
      acc2 += __shfl_down(acc2, s);
      accc += __shfl_down(accc, s);
    }
    if (tid == 0) {
      atomicAdd(&d_out[3], acc2);
      atomicAdd(&d_out[0], acc2);
      atomicAdd(&d_out[1], accc * (1.0f / ((float)NPTS * (float)KNN)));
    }
  }
}

extern "C" void kernel_launch(void* const* d_in, const int* in_sizes, int n_in,
                              void* d_out, int out_size, void* d_ws,
                              size_t ws_size, hipStream_t stream) {
  const float* latent      = (const float*)d_in[0];
  const float* latent_norm = (const float*)d_in[1];
  const float* dist_X      = (const float*)d_in[2];
  const float* mask_X      = (const float*)d_in[3];
  float* out = (float*)d_out;

  // Workspace layout (all 16B-aligned).
  char* w = (char*)d_ws;
  float*          sq   = (float*)w;                    w += NPTS * 4;            // 32 KB
  unsigned short* Lh   = (unsigned short*)w;           w += NPTS * DIM * 2;      // 1 MB
  unsigned short* Ll   = (unsigned short*)w;           w += NPTS * DIM * 2;      // 1 MB
  int*            ecnt = (int*)w;                      w += NPTS * 4;            // 32 KB
  int*            ecol = (int*)w;                      w += NPTS * KNN * 4;      // 384 KB
  float*          edx  = (float*)w;                    w += NPTS * KNN * 4;      // 384 KB
  unsigned long long* topk = (unsigned long long*)w;   // 3 MB (CS=4)

  prep_kernel<<<NPTS * 8 / 256, 256, 0, stream>>>(latent, Lh, Ll, sq, ecnt, out);
  main_kernel<<<NWG_DZ, 256, 0, stream>>>(Lh, Ll, sq, topk, mask_X, dist_X,
                                          ecnt, ecol, edx);
  tail_kernel<<<NPTS * KNN / 256 + NPTS / 64, 256, 0, stream>>>(
      latent, latent_norm, dist_X, ecol, edx, topk, out);
}